// Round 10
// baseline (28.467 us; speedup 1.0000x reference)
//
#include <hip/hip_runtime.h>
#include <hip/hip_bf16.h>
#include <utility>

typedef __fp16 h2    __attribute__((ext_vector_type(2)));
typedef __fp16 v8h   __attribute__((ext_vector_type(8)));
typedef _Float16 v8f16 __attribute__((ext_vector_type(8)));
typedef float  v4f   __attribute__((ext_vector_type(4)));
typedef float  v16f  __attribute__((ext_vector_type(16)));

#define NT 5                      // n-tiles (160 cols: 136 real + 24 pad)
#define KTSTRIDE (NT * 64 * 8)    // shorts per kt slice = 2560
#define NCHUNK (12 * NT * 64)     // 16B chunks in U = 3840

__device__ __forceinline__ short h16(float f) {
    return __builtin_bit_cast(short, (_Float16)f);   // RNE f32->f16
}

__device__ __forceinline__ void gload16(const short* g, short* l) {
    __builtin_amdgcn_global_load_lds(
        (const __attribute__((address_space(1))) unsigned int*)g,
        (__attribute__((address_space(3))) unsigned int*)l, 16, 0, 0);
}

__device__ __forceinline__ v8h pack4(h2 a, h2 b, h2 c, h2 d) {
    union { int4 i; v8h h; } u;
    u.i = make_int4(__builtin_bit_cast(int, a), __builtin_bit_cast(int, b),
                    __builtin_bit_cast(int, c), __builtin_bit_cast(int, d));
    return u.h;
}

__device__ __forceinline__ v16f mfma_f16(v8h a, v8h b, v16f c) {
    return __builtin_amdgcn_mfma_f32_32x32x16_f16(
        __builtin_bit_cast(v8f16, a), __builtin_bit_cast(v8f16, b), c, 0, 0, 0);
}

// tri-pack mapping: col n (0..135) <-> (p<=q)
constexpr int pof(int n) {
    int p = 0, b = 0;
    while (b + (16 - p) <= n) { b += 16 - p; ++p; }
    return p;
}
constexpr int qof(int n) {
    int p = 0, b = 0;
    while (b + (16 - p) <= n) { b += 16 - p; ++p; }
    return p + (n - b);
}

// compile-time component extract from 4x v4f (registers, no dynamic index)
template<int I>
__device__ __forceinline__ float xi(v4f f0, v4f f1, v4f f2, v4f f3) {
    if constexpr (I < 4)       return f0[I];
    else if constexpr (I < 8)  return f1[I - 4];
    else if constexpr (I < 12) return f2[I - 8];
    else                       return f3[I - 12];
}

template<int N>
__device__ __forceinline__ float gg(v4f f0, v4f f1, v4f f2, v4f f3) {
    if constexpr (N >= 136) return 0.f;
    else return xi<pof(N)>(f0, f1, f2, f3) * xi<qof(N)>(f0, f1, f2, f3);
}

// epilogue for one n-tile: s += acc[rg] * x_p(n)*x_q(n), n = NTI*32 + row(rg,h)
template<int NTI, int... RG>
__device__ __forceinline__ float epi_impl(const v16f& a, v4f f0, v4f f1, v4f f2, v4f f3,
                                          int h, std::integer_sequence<int, RG...>) {
    float s = 0.f;
    ((s = fmaf(a[RG],
               h ? gg<NTI * 32 + (RG & 3) + 8 * (RG >> 2) + 4>(f0, f1, f2, f3)
                 : gg<NTI * 32 + (RG & 3) + 8 * (RG >> 2)>(f0, f1, f2, f3),
               s)), ...);
    return s;
}
template<int NTI>
__device__ __forceinline__ float epi(const v16f& a, v4f f0, v4f f1, v4f f2, v4f f3, int h) {
    return epi_impl<NTI>(a, f0, f1, f2, f3, h, std::make_integer_sequence<int, 16>{});
}

// ---------------------------------------------------------------------------
// Prep: symmetrized U3/U2 -> fragment-ordered fp16 A-matrix (tri-packed n rows).
// Layout: Bg[kt(12)][nt(5)][lane(64)][j(8)] u16; at lane: n = lane&31 (+nt*32),
// i = 8*(lane>>5) + j. kt=11: U2sym at h=0, j=k2<4, rest zero.
// ---------------------------------------------------------------------------
__global__ void symcon_prep(const float* __restrict__ U3, const float* __restrict__ U2,
                            short* __restrict__ Bg)
{
    const int g = blockIdx.x * 256 + threadIdx.x;   // 0..2559
    if (g >= 160 * 16) return;
    const int n = g >> 4;                           // column 0..159
    const int i = g & 15;
    const int nt = n >> 5, lb = n & 31;
    const int lane = lb | ((i >> 3) << 5), j = i & 7;
    short* dst = Bg + (nt * 64 + lane) * 8 + j;
    if (n < 136) {
        int p = 0, base = 0;
        while (base + (16 - p) <= n) { base += 16 - p; ++p; }
        const int q = p + (n - base);
        const float* up = U3 + ((p * 16 + q) * 16 + i) * 11;
        const float* uq = U3 + ((q * 16 + p) * 16 + i) * 11;
        #pragma unroll
        for (int k3 = 0; k3 < 11; ++k3)
            dst[k3 * KTSTRIDE] = h16(up[k3] + (p != q ? uq[k3] : 0.f));
        if (i == 0) {
            short* d0 = Bg + 11 * KTSTRIDE + (nt * 64 + lb) * 8;
            #pragma unroll
            for (int jj = 0; jj < 4; ++jj)
                d0[jj] = h16(U2[(p * 16 + q) * 4 + jj] + (p != q ? U2[(q * 16 + p) * 4 + jj] : 0.f));
            #pragma unroll
            for (int jj = 4; jj < 8; ++jj) d0[jj] = 0;
            short* d1 = Bg + 11 * KTSTRIDE + (nt * 64 + lb + 32) * 8;
            #pragma unroll
            for (int jj = 0; jj < 8; ++jj) d1[jj] = 0;
        }
    } else {
        #pragma unroll
        for (int k3 = 0; k3 < 11; ++k3) dst[k3 * KTSTRIDE] = 0;
        if (i == 0) {
            short* d0 = Bg + 11 * KTSTRIDE + (nt * 64 + lb) * 8;
            short* d1 = Bg + 11 * KTSTRIDE + (nt * 64 + lb + 32) * 8;
            #pragma unroll
            for (int jj = 0; jj < 8; ++jj) { d0[jj] = 0; d1[jj] = 0; }
        }
    }
}

// ---------------------------------------------------------------------------
// Main: 256-thread block = 4 waves = 2 nodes x 2 wave-per-node; each wave owns
// 64 channels (two 32-col B operands). U (60 KB) staged once to LDS, ONE
// barrier, then free-running: per kt, 5 shared ds_read_b128 feed 10 MFMAs.
// Register-only quadratic epilogue (x reloaded from L2 at epilogue).
// ---------------------------------------------------------------------------
__global__ __launch_bounds__(256, 2)
void symcon_main(const float* __restrict__ x, const float* __restrict__ y,
                 const float* __restrict__ U1, const float* __restrict__ W3,
                 const float* __restrict__ W2, const float* __restrict__ W1,
                 const short* __restrict__ Bg, float* __restrict__ out)
{
    __shared__ __align__(16) short Ul[NCHUNK * 8];   // 61440 B

    const int tid  = threadIdx.x;
    const int lane = tid & 63;
    const int wid  = tid >> 6;            // 0..3
    const int node = blockIdx.x * 2 + (wid >> 1);
    const int chp  = wid & 1;             // channel pair: chans chp*64 .. chp*64+63
    const int col  = lane & 31;
    const int h    = lane >> 5;
    const int m0   = chp * 64 + col;
    const int m1   = m0 + 32;

    // ---- stage U into LDS: 3840 chunks = 15 per thread, lane-linear ----
    #pragma unroll
    for (int jj = 0; jj < 15; ++jj) {
        const int c = jj * 256 + tid;
        gload16(Bg + c * 8, &Ul[c * 8]);
    }

    // ---- species (argmax, first-max wins); wave-uniform ----
    int e = 0;
    {
        const float* yr = y + node * 10;
        float best = yr[0];
        #pragma unroll
        for (int s2 = 1; s2 < 10; ++s2) { const float v = yr[s2]; if (v > best) { best = v; e = s2; } }
    }

    // ---- lane's x halves (i = 8h..8h+7) for m0, m1 -> packed fp16 ----
    h2 xh0[4], xh1[4];
    {
        const float* xb = x + ((size_t)node * 128) * 16;
        const v4f lo0 = *reinterpret_cast<const v4f*>(xb + m0 * 16 + h * 8);
        const v4f hi0 = *reinterpret_cast<const v4f*>(xb + m0 * 16 + h * 8 + 4);
        const v4f lo1 = *reinterpret_cast<const v4f*>(xb + m1 * 16 + h * 8);
        const v4f hi1 = *reinterpret_cast<const v4f*>(xb + m1 * 16 + h * 8 + 4);
        xh0[0] = h2{(__fp16)lo0[0], (__fp16)lo0[1]};
        xh0[1] = h2{(__fp16)lo0[2], (__fp16)lo0[3]};
        xh0[2] = h2{(__fp16)hi0[0], (__fp16)hi0[1]};
        xh0[3] = h2{(__fp16)hi0[2], (__fp16)hi0[3]};
        xh1[0] = h2{(__fp16)lo1[0], (__fp16)lo1[1]};
        xh1[1] = h2{(__fp16)lo1[2], (__fp16)lo1[3]};
        xh1[2] = h2{(__fp16)hi1[0], (__fp16)hi1[1]};
        xh1[3] = h2{(__fp16)hi1[2], (__fp16)hi1[3]};
    }

    // ---- per-lane weights for both channel sets ----
    float w3a[11], w3b[11], w2a[4], w2b[4];
    #pragma unroll
    for (int k = 0; k < 11; ++k) {
        w3a[k] = W3[(e * 11 + k) * 128 + m0];
        w3b[k] = W3[(e * 11 + k) * 128 + m1];
    }
    #pragma unroll
    for (int k = 0; k < 4; ++k) {
        w2a[k] = W2[(e * 4 + k) * 128 + m0];
        w2b[k] = W2[(e * 4 + k) * 128 + m1];
    }

    __syncthreads();   // U staged (drains vmcnt); the ONLY barrier

    v16f aA[NT] = {}, aB[NT] = {};

    // ---- K loop: 12 kt x 5 nt; 5 shared A-frags feed 10 MFMAs ----
    const short* Up = Ul + lane * 8;
    #pragma unroll
    for (int kt = 0; kt < 12; ++kt) {
        v8h u[NT];
        #pragma unroll
        for (int t = 0; t < NT; ++t)
            u[t] = *reinterpret_cast<const v8h*>(Up + (kt * NT + t) * 512);
        v8h b0, b1;
        if (kt < 11) {
            const __fp16 wa = (__fp16)w3a[kt];
            const __fp16 wb = (__fp16)w3b[kt];
            const h2 wha = h2{wa, wa};
            const h2 whb = h2{wb, wb};
            b0 = pack4(xh0[0] * wha, xh0[1] * wha, xh0[2] * wha, xh0[3] * wha);
            b1 = pack4(xh1[0] * whb, xh1[1] * whb, xh1[2] * whb, xh1[3] * whb);
        } else {
            const h2 z = {};
            const h2 p00 = h ? z : h2{(__fp16)w2a[0], (__fp16)w2a[1]};
            const h2 p01 = h ? z : h2{(__fp16)w2a[2], (__fp16)w2a[3]};
            const h2 p10 = h ? z : h2{(__fp16)w2b[0], (__fp16)w2b[1]};
            const h2 p11 = h ? z : h2{(__fp16)w2b[2], (__fp16)w2b[3]};
            b0 = pack4(p00, p01, z, z);
            b1 = pack4(p10, p11, z, z);
        }
        #pragma unroll
        for (int t = 0; t < NT; ++t) {
            aA[t] = mfma_f16(u[t], b0, aA[t]);
            aB[t] = mfma_f16(u[t], b1, aB[t]);
        }
    }

    // ---- epilogue (register-only), x reloaded from L1/L2 ----
    const v4f u1q0 = *reinterpret_cast<const v4f*>(U1);
    const v4f u1q1 = *reinterpret_cast<const v4f*>(U1 + 4);
    const v4f u1q2 = *reinterpret_cast<const v4f*>(U1 + 8);
    const v4f u1q3 = *reinterpret_cast<const v4f*>(U1 + 12);

    float s0, s1, lin0, lin1;
    {
        const float* xp = x + ((size_t)node * 128 + m0) * 16;
        const v4f f0 = *reinterpret_cast<const v4f*>(xp);
        const v4f f1 = *reinterpret_cast<const v4f*>(xp + 4);
        const v4f f2 = *reinterpret_cast<const v4f*>(xp + 8);
        const v4f f3 = *reinterpret_cast<const v4f*>(xp + 12);
        s0 = epi<0>(aA[0], f0, f1, f2, f3, h) + epi<1>(aA[1], f0, f1, f2, f3, h)
           + epi<2>(aA[2], f0, f1, f2, f3, h) + epi<3>(aA[3], f0, f1, f2, f3, h)
           + epi<4>(aA[4], f0, f1, f2, f3, h);
        const v4f d = f0 * u1q0 + f1 * u1q1 + f2 * u1q2 + f3 * u1q3;
        lin0 = (d[0] + d[1] + d[2] + d[3]) * W1[e * 128 + m0];
    }
    {
        const float* xp = x + ((size_t)node * 128 + m1) * 16;
        const v4f f0 = *reinterpret_cast<const v4f*>(xp);
        const v4f f1 = *reinterpret_cast<const v4f*>(xp + 4);
        const v4f f2 = *reinterpret_cast<const v4f*>(xp + 8);
        const v4f f3 = *reinterpret_cast<const v4f*>(xp + 12);
        s1 = epi<0>(aB[0], f0, f1, f2, f3, h) + epi<1>(aB[1], f0, f1, f2, f3, h)
           + epi<2>(aB[2], f0, f1, f2, f3, h) + epi<3>(aB[3], f0, f1, f2, f3, h)
           + epi<4>(aB[4], f0, f1, f2, f3, h);
        const v4f d = f0 * u1q0 + f1 * u1q1 + f2 * u1q2 + f3 * u1q3;
        lin1 = (d[0] + d[1] + d[2] + d[3]) * W1[e * 128 + m1];
    }

    s0 += __shfl_xor(s0, 32);   // combine h=0/h=1 n-halves
    s1 += __shfl_xor(s1, 32);

    if (h == 0) {
        out[(size_t)node * 128 + m0] = s0 + lin0;
        out[(size_t)node * 128 + m1] = s1 + lin1;
    }
}

extern "C" void kernel_launch(void* const* d_in, const int* in_sizes, int n_in,
                              void* d_out, int out_size, void* d_ws, size_t ws_size,
                              hipStream_t stream) {
    const float* x  = (const float*)d_in[0];
    const float* y  = (const float*)d_in[1];
    const float* U3 = (const float*)d_in[2];
    const float* U2 = (const float*)d_in[3];
    const float* U1 = (const float*)d_in[4];
    const float* W3 = (const float*)d_in[5];
    const float* W2 = (const float*)d_in[6];
    const float* W1 = (const float*)d_in[7];
    short* Bg = (short*)d_ws;   // 12*2560 shorts = 60 KB fp16 Usym

    symcon_prep<<<10, 256, 0, stream>>>(U3, U2, Bg);
    symcon_main<<<1024, 256, 0, stream>>>(x, y, U1, W3, W2, W1, Bg, (float*)d_out);
}